// Round 12
// baseline (446.850 us; speedup 1.0000x reference)
//
#include <hip/hip_runtime.h>
#include <hip/hip_bf16.h>

#define FEAT 256
#define HID 128
#define CLASSES 32
#define LAYERS 3

typedef float f4 __attribute__((ext_vector_type(4)));
typedef float f2 __attribute__((ext_vector_type(2)));
typedef __attribute__((ext_vector_type(8))) short short8;
typedef __attribute__((ext_vector_type(4))) float f32x4;
typedef unsigned int u32;
typedef __attribute__((ext_vector_type(4))) unsigned int u32x4;

// fp32 -> bf16 RNE
__device__ __forceinline__ unsigned short bf16_rne(float v) {
    unsigned u = __float_as_uint(v);
    return (unsigned short)((u + 0x7FFF + ((u >> 16) & 1)) >> 16);
}
// pack two fp32 -> u32 of 2 bf16 (elem0 low, elem1 high)
__device__ __forceinline__ u32 bf16x2_rne(float a, float b) {
    return (u32)bf16_rne(a) | ((u32)bf16_rne(b) << 16);
}

// ---------------- CSR build ----------------

__global__ void count_kernel(const int* __restrict__ dst, int* __restrict__ counts, int E) {
    int e = blockIdx.x * blockDim.x + threadIdx.x;
    if (e < E) atomicAdd(&counts[dst[e]], 1);
}

__global__ void partial_kernel(const int* __restrict__ counts, int* __restrict__ partials, int N) {
    int t = threadIdx.x;
    int i = blockIdx.x * 256 + t;
    int v = (i < N) ? counts[i] : 0;
#pragma unroll
    for (int off = 32; off >= 1; off >>= 1) v += __shfl_down(v, off, 64);
    __shared__ int ws[4];
    if ((t & 63) == 0) ws[t >> 6] = v;
    __syncthreads();
    if (t == 0) partials[blockIdx.x] = ws[0] + ws[1] + ws[2] + ws[3];
}

__global__ void scan_partials_kernel(const int* __restrict__ partials, int* __restrict__ poff, int NB) {
    int t = threadIdx.x, lane = t & 63, w = t >> 6;
    int v = (t < NB) ? partials[t] : 0;
    int x = v;
#pragma unroll
    for (int off = 1; off < 64; off <<= 1) {
        int y = __shfl_up(x, off, 64);
        if (lane >= off) x += y;
    }
    __shared__ int ws[4];
    if (lane == 63) ws[w] = x;
    __syncthreads();
    int woff = 0;
    for (int k = 0; k < w; ++k) woff += ws[k];
    if (t < NB) poff[t] = woff + x - v;
}

__global__ void scan_final_kernel(const int* __restrict__ counts, const int* __restrict__ poff,
                                  int* __restrict__ row_off, int* __restrict__ cursor, int N) {
    int t = threadIdx.x, lane = t & 63, w = t >> 6;
    int i = blockIdx.x * 256 + t;
    int v = (i < N) ? counts[i] : 0;
    int x = v;
#pragma unroll
    for (int off = 1; off < 64; off <<= 1) {
        int y = __shfl_up(x, off, 64);
        if (lane >= off) x += y;
    }
    __shared__ int ws[4];
    if (lane == 63) ws[w] = x;
    __syncthreads();
    int woff = 0;
    for (int k = 0; k < w; ++k) woff += ws[k];
    int excl = poff[blockIdx.x] + woff + x - v;
    if (i < N) {
        row_off[i] = excl;
        cursor[i] = excl;
        if (i == N - 1) row_off[N] = excl + v;
    }
}

__global__ void fill_kernel(const int* __restrict__ src, const int* __restrict__ dst,
                            int* __restrict__ cursor, int* __restrict__ csr_src, int E) {
    int e = blockIdx.x * blockDim.x + threadIdx.x;
    if (e < E) {
        int pos = atomicAdd(&cursor[dst[e]], 1);
        csr_src[pos] = src[e];
    }
}

// ---------------- weight prep (merged): transposed single-bf16 tables ----------------
// we: [n=128][k=256] from emb_w[k][n]
// wl: 3 x [n=128][k=256]; k<128 -> rel_w[l][k][n], k>=128 -> root_w[l][k-128][n]
// wp: [c=64][k=128]; c<32 -> head_w[k][c], else head_w[128+k][c-32]
__global__ void prep_kernel(const float* __restrict__ emb_w, const float* __restrict__ rel_w,
                            const float* __restrict__ root_w, const float* __restrict__ head_w,
                            unsigned short* __restrict__ we, unsigned short* __restrict__ wl,
                            unsigned short* __restrict__ wp) {
    int idx = blockIdx.x * 256 + threadIdx.x;
    if (idx < 128 * 256) {
        int n = idx >> 8, k = idx & 255;
        we[n * 256 + k] = bf16_rne(emb_w[k * 128 + n]);
    } else if (idx < 4 * 128 * 256) {
        int i = idx - 128 * 256;
        int l = i >> 15;
        int r = i & 32767;
        int n = r >> 8, k = r & 255;
        float v = (k < 128) ? rel_w[l * 16384 + k * 128 + n] : root_w[l * 16384 + (k - 128) * 128 + n];
        wl[i] = bf16_rne(v);
    } else if (idx < 4 * 128 * 256 + 64 * 128) {
        int i = idx - 4 * 128 * 256;
        int c = i >> 7, k = i & 127;
        float v = (c < 32) ? head_w[k * 32 + c] : head_w[(128 + k) * 32 + (c - 32)];
        wp[c * 128 + k] = bf16_rne(v);
    }
}

// ---------------- feat fp32 -> bf16 (one-time, lets embed GEMM use the lean bf16-A path) ----------------
__global__ void cvt_feat_kernel(const float* __restrict__ f, unsigned short* __restrict__ o, int n8) {
    int i = blockIdx.x * 256 + threadIdx.x;
    if (i >= n8) return;
    f4 a = *(const f4*)(f + (size_t)i * 8);
    f4 b = *(const f4*)(f + (size_t)i * 8 + 4);
    short8 s;
    s[0] = (short)bf16_rne(a[0]); s[1] = (short)bf16_rne(a[1]);
    s[2] = (short)bf16_rne(a[2]); s[3] = (short)bf16_rne(a[3]);
    s[4] = (short)bf16_rne(b[0]); s[5] = (short)bf16_rne(b[1]);
    s[6] = (short)bf16_rne(b[2]); s[7] = (short)bf16_rne(b[3]);
    *(short8*)(o + (size_t)i * 8) = s;
}

// ---------------- MFMA bf16 GEMM: register-B 16-col waves, zero LDS / zero barriers ----------------
// out[M x NCOL] = act( concatK(A0|A1)[M x KTOT] @ W[KTOT x NCOL] + bias ), A bf16.
// W pre-transposed single bf16: W[n][k] (n-major, stride KTOT).
// Grid = (ceil(M/64), NCOL/64); block = 256 threads = 4 waves.
// Wave w owns cols [blockIdx.y*64 + w*16, +16) x rows [blockIdx.x*64, +64).
// B panel per wave = NCHUNK x short8 = 32 VGPR (KTOT=256) -- small enough that
// regalloc KEEPS it resident (round-9's 2-panel variant demanded ~170 VGPR and
// was rematerialized; this is the fix). acc = 16 VGPR, A tile = 32 VGPR.
// 4 row-tiles of 16x16 each: load 8 independent A frags, 8 MFMAs, store at end.
// No LDS, no barriers; ~6 blocks/CU (=24 waves/CU) hides latency via TLP.
template <int NCOL, int KTOT, bool RELU, bool PACKOUT>
__global__ __launch_bounds__(256) void gemm_reg(
    const unsigned short* __restrict__ A0, int lda0,
    const unsigned short* __restrict__ A1, int lda1, int K0,
    const unsigned short* __restrict__ W,
    const float* __restrict__ bias, void* __restrict__ outv, int M) {
    constexpr int NCHUNK = KTOT / 32;

    int wv = threadIdx.x >> 6;
    int lane = threadIdx.x & 63;
    int m16 = lane & 15;
    int quad = lane >> 4;
    int colbase = blockIdx.y * 64 + wv * 16;
    int rowblk = blockIdx.x * 64;

    // B panel -> registers (lane m16 = col, quad*8 = k-offset within chunk)
    short8 Bf[NCHUNK];
#pragma unroll
    for (int kc = 0; kc < NCHUNK; ++kc)
        Bf[kc] = *(const short8*)(const void*)(W + (size_t)(colbase + m16) * KTOT + kc * 32 + quad * 8);

    float bcol = bias ? bias[colbase + m16] : 0.f;

    f32x4 acc[4] = {};

#pragma unroll
    for (int t = 0; t < 4; ++t) {
        int r = rowblk + t * 16 + m16;
        r = (r < M) ? r : (M - 1);  // clamp reads; stores guarded below
        // 8 independent A-fragment loads (one L2 round-trip, amortized over the tile)
        short8 Af[NCHUNK];
#pragma unroll
        for (int kc = 0; kc < NCHUNK; ++kc) {
            bool second = (kc * 32 >= K0);
            const unsigned short* Ab = second ? A1 : A0;
            int lda = second ? lda1 : lda0;
            int kofs = kc * 32 - (second ? K0 : 0);
            Af[kc] = *(const short8*)(const void*)(Ab + (size_t)r * lda + kofs + quad * 8);
        }
#pragma unroll
        for (int kc = 0; kc < NCHUNK; ++kc)
            acc[t] = __builtin_amdgcn_mfma_f32_16x16x32_bf16(Af[kc], Bf[kc], acc[t], 0, 0, 0);
    }

    // epilogue: C/D layout col = lane&15, row = quad*4 + reg
#pragma unroll
    for (int t = 0; t < 4; ++t) {
#pragma unroll
        for (int r = 0; r < 4; ++r) {
            int row = rowblk + t * 16 + quad * 4 + r;
            if (row < M) {
                float v = acc[t][r] + bcol;
                if (RELU) v = fmaxf(v, 0.f);
                size_t idx = (size_t)row * NCOL + colbase + m16;
                if (PACKOUT) ((unsigned short*)outv)[idx] = bf16_rne(v);
                else ((float*)outv)[idx] = v;
            }
        }
    }
}

// ---------------- aggregation (CSR gather-sum, bf16 rows, 8-wide masked MLP) ----------------
// x rows are bf16 [N][128] (u32 = 2 elems/lane, 64 lanes = full row, 256B/gather).
__global__ void aggregate_kernel(const u32* __restrict__ x, const int* __restrict__ row_off,
                                 const int* __restrict__ csr, u32* __restrict__ agg, int N) {
    int gw = (blockIdx.x * 256 + threadIdx.x) >> 6;
    int lane = threadIdx.x & 63;
    if (gw >= N) return;
    int beg = row_off[gw], end = row_off[gw + 1];

    if (end <= beg) {
        agg[(size_t)gw * 64 + lane] = 0u;
        return;
    }

    auto unp = [](u32 u) -> f2 {
        f2 r;
        r[0] = __uint_as_float(u << 16);
        r[1] = __uint_as_float(u & 0xFFFF0000u);
        return r;
    };

    f2 a[8];
#pragma unroll
    for (int k = 0; k < 8; ++k) a[k] = (f2)0.f;

    int e1 = end - 1;
    int s[8];
#pragma unroll
    for (int k = 0; k < 8; ++k) s[k] = csr[min(beg + k, e1)];

    int j = beg;
    while (j < end) {
        u32 v[8];
#pragma unroll
        for (int k = 0; k < 8; ++k) v[k] = x[(size_t)s[k] * 64 + lane];

        int jn = j + 8;
        if (jn < end) {
#pragma unroll
            for (int k = 0; k < 8; ++k) s[k] = csr[min(jn + k, e1)];
        }

#pragma unroll
        for (int k = 0; k < 8; ++k)
            if (j + k < end) a[k] += unp(v[k]);

        j = jn;
    }

    f2 r = ((a[0] + a[4]) + (a[1] + a[5])) + ((a[2] + a[6]) + (a[3] + a[7]));
    agg[(size_t)gw * 64 + lane] = bf16x2_rne(r[0], r[1]);
}

// ---------------- edge head ----------------
// out[e][c] = pspd[src[e]][c] + pspd[dst[e]][32+c] + head_b[c]
__global__ void edge_out_kernel(const int* __restrict__ src, const int* __restrict__ dst,
                                const float* __restrict__ pspd, const float* __restrict__ head_b,
                                float* __restrict__ out, int E) {
    int idx = blockIdx.x * blockDim.x + threadIdx.x;
    int e = idx >> 3;
    int c4 = (idx & 7) * 4;
    if (e >= E) return;
    int s = src[e], d = dst[e];
    f4 a = *(const f4*)&pspd[(size_t)s * 64 + c4];
    f4 b = *(const f4*)&pspd[(size_t)d * 64 + 32 + c4];
    f4 hb = *(const f4*)&head_b[c4];
    f4 o = a + b + hb;
    *(f4*)&out[(size_t)e * CLASSES + c4] = o;
}

// ---------------- launcher ----------------

extern "C" void kernel_launch(void* const* d_in, const int* in_sizes, int n_in,
                              void* d_out, int out_size, void* d_ws, size_t ws_size,
                              hipStream_t stream) {
    const float* feat   = (const float*)d_in[0];
    const int*   eidx   = (const int*)d_in[1];
    const float* emb_w  = (const float*)d_in[2];
    const float* emb_b  = (const float*)d_in[3];
    const float* rel_w  = (const float*)d_in[4];
    const float* rel_b  = (const float*)d_in[5];
    const float* root_w = (const float*)d_in[6];
    const float* head_w = (const float*)d_in[7];
    const float* head_b = (const float*)d_in[8];
    float* out = (float*)d_out;

    int N = in_sizes[0] / FEAT;
    int E = in_sizes[1] / 2;
    const int* src = eidx;
    const int* dst = eidx + E;

    // workspace layout: bf16 activation buffers (as u32 regions), bf16 feat copy,
    // pspd fp32 aliases agg, then ints, then single-bf16 weight tables
    u32* xA    = (u32*)d_ws;                   // N*64 u32 = N*128 bf16
    u32* xB    = xA + (size_t)N * 64;          // N*64 u32
    u32* agg   = xB + (size_t)N * 64;          // N*64 u32 (pspd aliases: N*64 fp32)
    u32* featb = agg + (size_t)N * 64;         // N*128 u32 = N*256 bf16
    int* counts   = (int*)(featb + (size_t)N * 128);  // N
    int* row_off  = counts + N;                       // N+1
    int* cursor   = row_off + (N + 1);                // N
    int* csr_src  = cursor + N;                       // E
    int* partials = csr_src + E;                      // 256
    int* poff     = partials + 256;                   // 256
    int* iend     = poff + 256;
    // pad int region to 16B boundary
    size_t ioff = (size_t)(iend - (int*)d_ws);
    ioff = (ioff + 3) & ~(size_t)3;
    unsigned short* we = (unsigned short*)((int*)d_ws + ioff);  // 128*256
    unsigned short* wl = we + 128 * 256;                        // 3*128*256
    unsigned short* wp = wl + 3 * 128 * 256;                    // 64*128

    int NB = (N + 255) / 256;

    hipMemsetAsync(counts, 0, (size_t)N * sizeof(int), stream);
    count_kernel<<<(E + 255) / 256, 256, 0, stream>>>(dst, counts, E);
    partial_kernel<<<NB, 256, 0, stream>>>(counts, partials, N);
    scan_partials_kernel<<<1, 256, 0, stream>>>(partials, poff, NB);
    scan_final_kernel<<<NB, 256, 0, stream>>>(counts, poff, row_off, cursor, N);
    fill_kernel<<<(E + 255) / 256, 256, 0, stream>>>(src, dst, cursor, csr_src, E);

    prep_kernel<<<(4 * 128 * 256 + 64 * 128 + 255) / 256, 256, 0, stream>>>(
        emb_w, rel_w, root_w, head_w, we, wl, wp);
    cvt_feat_kernel<<<(N * 32 + 255) / 256, 256, 0, stream>>>(feat, (unsigned short*)featb, N * 32);

    int gm = (N + 63) / 64;
    // embed: xA = bf16(relu(featb @ emb_w + emb_b))
    gemm_reg<HID, FEAT, true, true><<<dim3(gm, HID / 64), 256, 0, stream>>>(
        (const unsigned short*)featb, FEAT, nullptr, 0, FEAT, we, emb_b, xA, N);

    const u32* xin = xA;
    u32* xout = xB;
    for (int l = 0; l < LAYERS; ++l) {
        aggregate_kernel<<<(N * 64 + 255) / 256, 256, 0, stream>>>(xin, row_off, csr_src, agg, N);
        gemm_reg<HID, 2 * HID, true, true><<<dim3(gm, HID / 64), 256, 0, stream>>>(
            (const unsigned short*)agg, HID, (const unsigned short*)xin, HID, HID,
            wl + (size_t)l * 128 * 256, rel_b + (size_t)l * HID, xout, N);
        u32* tmp = (u32*)xin; xin = xout; xout = tmp;
    }

    // pspd = x @ Wpp (no bias/relu), fp32 out; aliases agg
    float* pspd = (float*)agg;
    gemm_reg<64, HID, false, false><<<dim3(gm, 1), 256, 0, stream>>>(
        (const unsigned short*)xin, HID, nullptr, 0, HID, wp, nullptr, pspd, N);

    edge_out_kernel<<<((size_t)E * 8 + 255) / 256, 256, 0, stream>>>(src, dst, pspd, head_b, out, E);
}